// Round 13
// baseline (1160.707 us; speedup 1.0000x reference)
//
#include <hip/hip_runtime.h>

// LIIFParametric3DConv — round 13: cooperative MFMA MLP (occupancy fix).
// R12's mlp was latency-bound: 64 KB LDS -> 2 blocks/CU -> 2 waves/SIMD
// (Occupancy 23%, MfmaUtil 13%, VALUBusy 22%). This round: one 32x256 h1
// tile (16 KB) SHARED by the block's 4 waves; layer 1 split by n-columns,
// layer 2 split by column-group, cross-wave W3 reduction in LDS; lerp fused.
// LDS ~17 KB -> 8 blocks/CU -> 32 waves/CU.
//
// ws layout (bytes):
//   fhi  @ 0          : 75,497,472  (589824 rows x 64ch bf16, hi)
//   flo  @ 75497472   : 75,497,472  (lo = bf16(f - hi))
//   W1T  @ 150994944  : 32,768      (256 n x 64 k bf16, hi)
//   W1L  @ 151027712  : 32,768      (lo part)
//   W2T  @ 151060480  : 131,072     (256 n x 256 k bf16)

using s16x8 = __attribute__((ext_vector_type(8))) short;
using f32x4 = __attribute__((ext_vector_type(4))) float;

__device__ __forceinline__ float bf2f(unsigned short u){
  return __uint_as_float(((unsigned)u) << 16);
}
__device__ __forceinline__ short f2bf(float f){
  unsigned b = __float_as_uint(f);
  return (short)((b + 0x7FFFu + ((b >> 16) & 1u)) >> 16);
}

// ---------------- prep: W1 -> 256x64 hi/lo bf16, W2 -> 256x256 bf16 ---------
__global__ void prep_kernel(const float* __restrict__ W1, const float* __restrict__ W2,
                            short* __restrict__ W1T, short* __restrict__ W1L,
                            short* __restrict__ W2T){
  const int n = threadIdx.x; // 0..255
  for(int k=0;k<64;k++){
    const float w = W1[(size_t)k*256 + n];
    const short h = f2bf(w);
    W1T[n*64 + k] = h;
    W1L[n*64 + k] = f2bf(w - bf2f((unsigned short)h));
  }
  for(int k=0;k<256;k++) W2T[n*256 + k] = f2bf(W2[(size_t)k*256 + n]);
}

// ---------------- conv3d 2->64, 3x3x3, SAME; writes hi/lo bf16 --------------
__global__ __launch_bounds__(256) void conv_kernel(
    const float* __restrict__ xr, const float* __restrict__ xi,
    const float* __restrict__ enc_w, const float* __restrict__ enc_b,
    short* __restrict__ fhi, short* __restrict__ flo)
{
  __shared__ __align__(16) float wl[64][56];
  __shared__ float bl[64];
  const int tid = threadIdx.x;
  for(int i=tid;i<3456;i+=256) wl[i/54][i%54] = enc_w[i];
  if(tid<128) wl[tid>>1][54+(tid&1)] = 0.f;
  if(tid<64)  bl[tid] = enc_b[tid];
  __syncthreads();

  const unsigned bi   = blockIdx.x;          // 2304 = 2*32*36
  const unsigned tile = bi % 36u;
  const unsigned t    = (bi/36u) % 32u;
  const unsigned b    = bi / 1152u;
  const int h = (int)((tile/6u)*16u) + (tid>>4);
  const int w = (int)((tile%6u)*16u) + (tid&15);

  float xv[56];
  xv[54]=0.f; xv[55]=0.f;
  int k=0;
  #pragma unroll
  for(int i=0;i<2;i++){
    const float* src = i ? xi : xr;
    #pragma unroll
    for(int dz=-1;dz<=1;dz++){
      const int tt = (int)t + dz;
      const bool tok = (tt>=0 && tt<32);
      const size_t tbase = (size_t)(b*32u + (unsigned)(tok?tt:0))*9216u;
      #pragma unroll
      for(int dy=-1;dy<=1;dy++){
        const int hh = h+dy;
        const bool hok = (hh>=0 && hh<96);
        #pragma unroll
        for(int dx=-1;dx<=1;dx++){
          const int ww = w+dx;
          const bool ok = tok && hok && (ww>=0 && ww<96);
          xv[k] = ok ? src[tbase + (size_t)(hh*96+ww)] : 0.f;
          k++;
        }
      }
    }
  }

  const unsigned idx = (b*32u+t)*9216u + (unsigned)(h*96+w);
  short* ph = fhi + (size_t)idx*64u;
  short* pl = flo + (size_t)idx*64u;
  #pragma unroll
  for(int g=0; g<4; g++){
    unsigned hw[8], lw[8];
    #pragma unroll
    for(int c2=0;c2<8;c2++){
      unsigned hpair=0, lpair=0;
      #pragma unroll
      for(int half=0; half<2; half++){
        const int c = g*16 + c2*2 + half;
        float acc = bl[c];
        const float4* wp = (const float4*)(&wl[c][0]);
        #pragma unroll
        for(int qq=0;qq<14;qq++){
          const float4 w4 = wp[qq];
          acc += w4.x*xv[qq*4+0] + w4.y*xv[qq*4+1]
               + w4.z*xv[qq*4+2] + w4.w*xv[qq*4+3];
        }
        const unsigned short hu = (unsigned short)f2bf(acc);
        const unsigned short lu = (unsigned short)f2bf(acc - bf2f(hu));
        hpair |= ((unsigned)hu) << (16*half);
        lpair |= ((unsigned)lu) << (16*half);
      }
      hw[c2]=hpair; lw[c2]=lpair;
    }
    uint4* dh = (uint4*)(ph + g*16);
    uint4* dl = (uint4*)(pl + g*16);
    dh[0] = make_uint4(hw[0],hw[1],hw[2],hw[3]);
    dh[1] = make_uint4(hw[4],hw[5],hw[6],hw[7]);
    dl[0] = make_uint4(lw[0],lw[1],lw[2],lw[3]);
    dl[1] = make_uint4(lw[4],lw[5],lw[6],lw[7]);
  }
}

// ---------------- cooperative MFMA MLP + fused lerp -------------------------
// Block = 4 waves, 32 evals (16 pixels). Shared 32x256 bf16 h1 tile.
// Layer 1: wave w computes n-columns [w*64, w*64+64). Layer 2: wave w does
// column-group w, partial preds reduced across waves via LDS.
__global__ __launch_bounds__(256) void mlp_kernel(
  const float* __restrict__ tcoord,
  const short* __restrict__ fhi, const short* __restrict__ flo,
  const short* __restrict__ W1T, const short* __restrict__ W1L,
  const float* __restrict__ W1,  const float* __restrict__ b1,
  const short* __restrict__ W2T, const float* __restrict__ b2,
  const float* __restrict__ W3,  const float* __restrict__ b3,
  float* __restrict__ out)
{
  __shared__ __align__(16) short hlds[32*256];  // 16 KB shared h1
  __shared__ unsigned evoffs[32];
  __shared__ float    tcs[32];
  __shared__ float    redbuf[4][32];

  const int tid  = threadIdx.x;
  const int wave = tid>>6;
  const int lane = tid&63;
  const int q  = lane>>4;   // quad
  const int ln = lane&15;
  const unsigned evbase = blockIdx.x*32u;
  const float dstep = 2.0f/31.0f;

  // ---- meta for the block's 32 evals ----
  if(tid < 32){
    const unsigned ev = evbase + (unsigned)tid;
    const unsigned pt = ev>>1;
    const unsigned fc = ev&1u;
    const unsigned wq = pt%96u;
    const unsigned hq = (pt/96u)%96u;
    const unsigned jq = (pt/9216u)%32u;
    const unsigned bq = pt/294912u;
    float tc = tcoord[bq*32u+jq];
    tc = fminf(fmaxf(tc, -1.0f), 1.0f - 1e-6f);
    const int ti = (int)floorf((tc+1.0f)/dstep);
    const unsigned trow = (unsigned)ti + fc;       // <= 31
    evoffs[tid] = (bq*32u+trow)*9216u + hq*96u + wq;
    tcs[tid] = tc;
  }
  __syncthreads();

  const unsigned off0 = evoffs[ln];
  const unsigned off1 = evoffs[16+ln];
  float tcm[2][4];
  #pragma unroll
  for(int rt=0;rt<2;rt++)
    #pragma unroll
    for(int rr=0;rr<4;rr++)
      tcm[rt][rr] = tcs[rt*16 + q*4 + rr];

  // ---- A1 fragments: A[m=ln][k=q*8+j], 2 row-tiles, hi+lo ----
  s16x8 ahi[2][2], alo[2][2];
  {
    const size_t o0 = (size_t)off0*64u + (size_t)(q*8);
    const size_t o1 = (size_t)off1*64u + (size_t)(q*8);
    ahi[0][0] = *(const s16x8*)(fhi+o0);    ahi[0][1] = *(const s16x8*)(fhi+o0+32);
    ahi[1][0] = *(const s16x8*)(fhi+o1);    ahi[1][1] = *(const s16x8*)(fhi+o1+32);
    alo[0][0] = *(const s16x8*)(flo+o0);    alo[0][1] = *(const s16x8*)(flo+o0+32);
    alo[1][0] = *(const s16x8*)(flo+o1);    alo[1][1] = *(const s16x8*)(flo+o1+32);
  }

  // ---- layer 1: wave handles nt = wave*4 .. wave*4+3 ----
  #pragma unroll
  for(int nti=0; nti<4; nti++){
    const int nt = wave*4 + nti;
    const int n = nt*16 + ln;
    const s16x8 bf0 = *(const s16x8*)(W1T + n*64 + q*8);
    const s16x8 bf1 = *(const s16x8*)(W1T + n*64 + 32 + q*8);
    const s16x8 bl0 = *(const s16x8*)(W1L + n*64 + q*8);
    const s16x8 bl1 = *(const s16x8*)(W1L + n*64 + 32 + q*8);
    const float w1l  = W1[(size_t)64*256 + n];
    const float bias = b1[n];
    const int g  = n>>3;
    const int ne = n&7;
    #pragma unroll
    for(int rt=0;rt<2;rt++){
      f32x4 acc = {0.f,0.f,0.f,0.f};
      acc = __builtin_amdgcn_mfma_f32_16x16x32_bf16(ahi[rt][0], bf0, acc, 0,0,0);
      acc = __builtin_amdgcn_mfma_f32_16x16x32_bf16(ahi[rt][1], bf1, acc, 0,0,0);
      acc = __builtin_amdgcn_mfma_f32_16x16x32_bf16(alo[rt][0], bf0, acc, 0,0,0);
      acc = __builtin_amdgcn_mfma_f32_16x16x32_bf16(alo[rt][1], bf1, acc, 0,0,0);
      acc = __builtin_amdgcn_mfma_f32_16x16x32_bf16(ahi[rt][0], bl0, acc, 0,0,0);
      acc = __builtin_amdgcn_mfma_f32_16x16x32_bf16(ahi[rt][1], bl1, acc, 0,0,0);
      #pragma unroll
      for(int rr=0;rr<4;rr++){
        const int m = rt*16 + q*4 + rr;            // D: row=q*4+reg, col=ln
        const float z = acc[rr] + tcm[rt][rr]*w1l + bias;
        // swizzled: element (m,n) at m*256 + ((n>>3)^(m&7))*8 + (n&7)
        hlds[m*256 + ((g ^ (m&7))<<3) + ne] = f2bf(__sinf(30.0f*z));
      }
    }
  }

  __syncthreads();   // all h1 columns visible to all waves

  // ---- layer 2 (+3 folded): wave handles column-group cg = wave ----
  float pacc[2][4];
  #pragma unroll
  for(int rt=0;rt<2;rt++)
    #pragma unroll
    for(int rr=0;rr<4;rr++) pacc[rt][rr]=0.f;

  {
    const int cg = wave;
    f32x4 acc[2][4];
    const f32x4 zv = {0.f,0.f,0.f,0.f};
    #pragma unroll
    for(int rt=0;rt<2;rt++)
      #pragma unroll
      for(int nt=0;nt<4;nt++) acc[rt][nt] = zv;

    #pragma unroll
    for(int ks=0; ks<8; ks++){
      s16x8 a2[2];
      #pragma unroll
      for(int rt=0;rt<2;rt++){
        const int m  = rt*16 + ln;
        const int gk = ks*4 + q;
        a2[rt] = *(const s16x8*)(hlds + m*256 + ((gk ^ (m&7))<<3));
      }
      s16x8 b2f[4];
      #pragma unroll
      for(int nt=0;nt<4;nt++){
        const int n = cg*64 + nt*16 + ln;
        b2f[nt] = *(const s16x8*)(W2T + n*256 + ks*32 + q*8);
      }
      #pragma unroll
      for(int rt=0;rt<2;rt++)
        #pragma unroll
        for(int nt=0;nt<4;nt++)
          acc[rt][nt] = __builtin_amdgcn_mfma_f32_16x16x32_bf16(a2[rt], b2f[nt], acc[rt][nt], 0,0,0);
    }
    #pragma unroll
    for(int nt=0;nt<4;nt++){
      const int n = cg*64 + nt*16 + ln;
      const float b2v = b2[n];
      const float w3v = W3[n];
      #pragma unroll
      for(int rt=0;rt<2;rt++)
        #pragma unroll
        for(int rr=0;rr<4;rr++){
          const float h2 = __sinf(30.0f*(acc[rt][nt][rr] + b2v));
          pacc[rt][rr] += h2*w3v;
        }
    }
  }

  // reduce over the 16 n-lanes of this wave's column-group
  #pragma unroll
  for(int rt=0;rt<2;rt++)
    #pragma unroll
    for(int rr=0;rr<4;rr++){
      float v = pacc[rt][rr];
      v += __shfl_xor(v, 1, 64);
      v += __shfl_xor(v, 2, 64);
      v += __shfl_xor(v, 4, 64);
      v += __shfl_xor(v, 8, 64);
      pacc[rt][rr] = v;
    }
  if(ln==0){
    #pragma unroll
    for(int rt=0;rt<2;rt++)
      #pragma unroll
      for(int rr=0;rr<4;rr++)
        redbuf[wave][rt*16 + q*4 + rr] = pacc[rt][rr];
  }
  __syncthreads();

  // ---- cross-wave sum + fused lerp: rows (2s,2s+1) -> pixel ----
  if(tid < 16){
    const int r0 = 2*tid, r1 = 2*tid+1;
    const float pf = redbuf[0][r0]+redbuf[1][r0]+redbuf[2][r0]+redbuf[3][r0];
    const float pc = redbuf[0][r1]+redbuf[1][r1]+redbuf[2][r1]+redbuf[3][r1];
    const float tcp = tcs[r0];
    const int tip = (int)floorf((tcp+1.0f)/dstep);
    const float fci = (float)((double)tip*(2.0/31.0) - 1.0);
    const float tau = (tcp - fci)/dstep;
    out[blockIdx.x*16u + (unsigned)tid] = pf*(1.0f-tau) + pc*tau + b3[0];
  }
}

extern "C" void kernel_launch(void* const* d_in, const int* in_sizes, int n_in,
                              void* d_out, int out_size, void* d_ws, size_t ws_size,
                              hipStream_t stream){
  const float* xr     = (const float*)d_in[0];
  const float* xi     = (const float*)d_in[1];
  const float* tcoord = (const float*)d_in[2];
  const float* enc_w  = (const float*)d_in[3];
  const float* enc_b  = (const float*)d_in[4];
  const float* W1     = (const float*)d_in[5];
  const float* b1     = (const float*)d_in[6];
  const float* W2     = (const float*)d_in[7];
  const float* b2     = (const float*)d_in[8];
  const float* W3     = (const float*)d_in[9];
  const float* b3     = (const float*)d_in[10];

  char* ws = (char*)d_ws;
  short* fhi  = (short*)(ws);
  short* flo  = (short*)(ws + 75497472);
  short* W1T  = (short*)(ws + 150994944);
  short* W1L  = (short*)(ws + 151027712);
  short* W2T  = (short*)(ws + 151060480);
  float* out  = (float*)d_out;

  hipLaunchKernelGGL(prep_kernel, dim3(1),     dim3(256), 0, stream, W1, W2, W1T, W1L, W2T);
  hipLaunchKernelGGL(conv_kernel, dim3(2304),  dim3(256), 0, stream, xr, xi, enc_w, enc_b, fhi, flo);
  hipLaunchKernelGGL(mlp_kernel,  dim3(36864), dim3(256), 0, stream, tcoord, fhi, flo,
                     W1T, W1L, W1, b1, W2T, b2, W3, b3, out);
}

// Round 14
// 1114.375 us; speedup vs baseline: 1.0416x; 1.0416x over previous
//
#include <hip/hip_runtime.h>

// LIIFParametric3DConv — round 14: barrier-free, software-pipelined MFMA MLP.
// R12/R13 both stuck at ~12% MfmaUtil independent of occupancy -> per-block
// latency convoys (barriers + serialized load epochs). This round: 1-wave
// blocks (64 thr) with a PRIVATE 16 KB h1 tile (no __syncthreads at all;
// same-wave LDS ordering via lgkmcnt), each wave loops over 4 tiles of 32
// evals with next-tile meta+A-fragment prefetch overlapping compute.
// LDS 16 KB/block -> 10 waves/CU; layer-1 nt-loop unroll 2 for dual W1T
// load streams. Lerp fused in epilogue. Prep parallelized.
//
// ws layout (bytes):
//   fhi  @ 0          : 75,497,472  (589824 rows x 64ch bf16, hi)
//   flo  @ 75497472   : 75,497,472  (lo = bf16(f - hi))
//   W1T  @ 150994944  : 32,768      (256 n x 64 k bf16, hi)
//   W1L  @ 151027712  : 32,768      (lo part)
//   W2T  @ 151060480  : 131,072     (256 n x 256 k bf16)

using s16x8 = __attribute__((ext_vector_type(8))) short;
using f32x4 = __attribute__((ext_vector_type(4))) float;

__device__ __forceinline__ float bf2f(unsigned short u){
  return __uint_as_float(((unsigned)u) << 16);
}
__device__ __forceinline__ short f2bf(float f){
  unsigned b = __float_as_uint(f);
  return (short)((b + 0x7FFFu + ((b >> 16) & 1u)) >> 16);
}

// ---------------- prep (parallel): W1 -> 256x64 hi/lo, W2 -> 256x256 --------
__global__ void prep1_kernel(const float* __restrict__ W1,
                             short* __restrict__ W1T, short* __restrict__ W1L){
  const int k = blockIdx.x;      // 0..63
  const int n = threadIdx.x;     // 0..255
  const float w = W1[(size_t)k*256 + n];
  const short h = f2bf(w);
  W1T[n*64 + k] = h;
  W1L[n*64 + k] = f2bf(w - bf2f((unsigned short)h));
}
__global__ void prep2_kernel(const float* __restrict__ W2, short* __restrict__ W2T){
  const int k = blockIdx.x;      // 0..255
  const int n = threadIdx.x;     // 0..255
  W2T[n*256 + k] = f2bf(W2[(size_t)k*256 + n]);
}

// ---------------- conv3d 2->64, 3x3x3, SAME; writes hi/lo bf16 --------------
__global__ __launch_bounds__(256) void conv_kernel(
    const float* __restrict__ xr, const float* __restrict__ xi,
    const float* __restrict__ enc_w, const float* __restrict__ enc_b,
    short* __restrict__ fhi, short* __restrict__ flo)
{
  __shared__ __align__(16) float wl[64][56];
  __shared__ float bl[64];
  const int tid = threadIdx.x;
  for(int i=tid;i<3456;i+=256) wl[i/54][i%54] = enc_w[i];
  if(tid<128) wl[tid>>1][54+(tid&1)] = 0.f;
  if(tid<64)  bl[tid] = enc_b[tid];
  __syncthreads();

  const unsigned bi   = blockIdx.x;          // 2304 = 2*32*36
  const unsigned tile = bi % 36u;
  const unsigned t    = (bi/36u) % 32u;
  const unsigned b    = bi / 1152u;
  const int h = (int)((tile/6u)*16u) + (tid>>4);
  const int w = (int)((tile%6u)*16u) + (tid&15);

  float xv[56];
  xv[54]=0.f; xv[55]=0.f;
  int k=0;
  #pragma unroll
  for(int i=0;i<2;i++){
    const float* src = i ? xi : xr;
    #pragma unroll
    for(int dz=-1;dz<=1;dz++){
      const int tt = (int)t + dz;
      const bool tok = (tt>=0 && tt<32);
      const size_t tbase = (size_t)(b*32u + (unsigned)(tok?tt:0))*9216u;
      #pragma unroll
      for(int dy=-1;dy<=1;dy++){
        const int hh = h+dy;
        const bool hok = (hh>=0 && hh<96);
        #pragma unroll
        for(int dx=-1;dx<=1;dx++){
          const int ww = w+dx;
          const bool ok = tok && hok && (ww>=0 && ww<96);
          xv[k] = ok ? src[tbase + (size_t)(hh*96+ww)] : 0.f;
          k++;
        }
      }
    }
  }

  const unsigned idx = (b*32u+t)*9216u + (unsigned)(h*96+w);
  short* ph = fhi + (size_t)idx*64u;
  short* pl = flo + (size_t)idx*64u;
  #pragma unroll
  for(int g=0; g<4; g++){
    unsigned hw[8], lw[8];
    #pragma unroll
    for(int c2=0;c2<8;c2++){
      unsigned hpair=0, lpair=0;
      #pragma unroll
      for(int half=0; half<2; half++){
        const int c = g*16 + c2*2 + half;
        float acc = bl[c];
        const float4* wp = (const float4*)(&wl[c][0]);
        #pragma unroll
        for(int qq=0;qq<14;qq++){
          const float4 w4 = wp[qq];
          acc += w4.x*xv[qq*4+0] + w4.y*xv[qq*4+1]
               + w4.z*xv[qq*4+2] + w4.w*xv[qq*4+3];
        }
        const unsigned short hu = (unsigned short)f2bf(acc);
        const unsigned short lu = (unsigned short)f2bf(acc - bf2f(hu));
        hpair |= ((unsigned)hu) << (16*half);
        lpair |= ((unsigned)lu) << (16*half);
      }
      hw[c2]=hpair; lw[c2]=lpair;
    }
    uint4* dh = (uint4*)(ph + g*16);
    uint4* dl = (uint4*)(pl + g*16);
    dh[0] = make_uint4(hw[0],hw[1],hw[2],hw[3]);
    dh[1] = make_uint4(hw[4],hw[5],hw[6],hw[7]);
    dl[0] = make_uint4(lw[0],lw[1],lw[2],lw[3]);
    dl[1] = make_uint4(lw[4],lw[5],lw[6],lw[7]);
  }
}

// ---------------- pipelined wave-autonomous MFMA MLP + fused lerp -----------
struct TileA {
  s16x8 ahi[2][2], alo[2][2];
  float tcm[2][4];
};

__device__ __forceinline__ void load_tile(
  unsigned tile, int lane, int q, int ln,
  const float* __restrict__ tcoord,
  const short* __restrict__ fhi, const short* __restrict__ flo,
  TileA& T)
{
  const float dstep = 2.0f/31.0f;
  const unsigned ev = tile*32u + (unsigned)(lane & 31);
  const unsigned pt = ev>>1;
  const unsigned fc = ev&1u;
  const unsigned wq = pt%96u;
  const unsigned hq = (pt/96u)%96u;
  const unsigned jq = (pt/9216u)%32u;
  const unsigned bq = pt/294912u;
  float tc = tcoord[bq*32u+jq];
  tc = fminf(fmaxf(tc, -1.0f), 1.0f - 1e-6f);
  const int ti = (int)floorf((tc+1.0f)/dstep);
  const unsigned trow = (unsigned)ti + fc;       // <= 31
  const unsigned rowoff = (bq*32u+trow)*9216u + hq*96u + wq;

  const unsigned off0 = __shfl(rowoff, ln, 64);       // row ln
  const unsigned off1 = __shfl(rowoff, 16+ln, 64);    // row 16+ln
  #pragma unroll
  for(int rt=0;rt<2;rt++)
    #pragma unroll
    for(int rr=0;rr<4;rr++)
      T.tcm[rt][rr] = __shfl(tc, rt*16 + q*4 + rr, 64);

  const size_t o0 = (size_t)off0*64u + (size_t)(q*8);
  const size_t o1 = (size_t)off1*64u + (size_t)(q*8);
  T.ahi[0][0] = *(const s16x8*)(fhi+o0);    T.ahi[0][1] = *(const s16x8*)(fhi+o0+32);
  T.ahi[1][0] = *(const s16x8*)(fhi+o1);    T.ahi[1][1] = *(const s16x8*)(fhi+o1+32);
  T.alo[0][0] = *(const s16x8*)(flo+o0);    T.alo[0][1] = *(const s16x8*)(flo+o0+32);
  T.alo[1][0] = *(const s16x8*)(flo+o1);    T.alo[1][1] = *(const s16x8*)(flo+o1+32);
}

__device__ __forceinline__ void compute_tile(
  const TileA& T, unsigned tile, int lane, int q, int ln,
  const short* __restrict__ W1T, const short* __restrict__ W1L,
  const float* __restrict__ W1,  const float* __restrict__ b1,
  const short* __restrict__ W2T, const float* __restrict__ b2,
  const float* __restrict__ W3,  float b3v,
  short* __restrict__ hlds, float* __restrict__ out)
{
  const float dstep = 2.0f/31.0f;

  // ---- layer 1: h1 = sin(30*(F@W1[0:64] + tc*W1[64] + b1)) ----
  #pragma unroll 2
  for(int nt=0; nt<16; nt++){
    const int n = nt*16 + ln;
    const s16x8 bf0 = *(const s16x8*)(W1T + n*64 + q*8);
    const s16x8 bf1 = *(const s16x8*)(W1T + n*64 + 32 + q*8);
    const s16x8 bl0 = *(const s16x8*)(W1L + n*64 + q*8);
    const s16x8 bl1 = *(const s16x8*)(W1L + n*64 + 32 + q*8);
    const float w1l  = W1[(size_t)64*256 + n];
    const float bias = b1[n];
    const int g  = n>>3;
    const int ne = n&7;
    #pragma unroll
    for(int rt=0;rt<2;rt++){
      f32x4 acc = {0.f,0.f,0.f,0.f};
      acc = __builtin_amdgcn_mfma_f32_16x16x32_bf16(T.ahi[rt][0], bf0, acc, 0,0,0);
      acc = __builtin_amdgcn_mfma_f32_16x16x32_bf16(T.ahi[rt][1], bf1, acc, 0,0,0);
      acc = __builtin_amdgcn_mfma_f32_16x16x32_bf16(T.alo[rt][0], bf0, acc, 0,0,0);
      acc = __builtin_amdgcn_mfma_f32_16x16x32_bf16(T.alo[rt][1], bf1, acc, 0,0,0);
      acc = __builtin_amdgcn_mfma_f32_16x16x32_bf16(T.ahi[rt][0], bl0, acc, 0,0,0);
      acc = __builtin_amdgcn_mfma_f32_16x16x32_bf16(T.ahi[rt][1], bl1, acc, 0,0,0);
      #pragma unroll
      for(int rr=0;rr<4;rr++){
        const int m = rt*16 + q*4 + rr;            // D: row=q*4+reg, col=ln
        const float z = acc[rr] + T.tcm[rt][rr]*w1l + bias;
        // swizzled: element (m,n) at m*256 + ((n>>3)^(m&7))*8 + (n&7)
        hlds[m*256 + ((g ^ (m&7))<<3) + ne] = f2bf(__sinf(30.0f*z));
      }
    }
  }
  // no barrier: same-wave LDS write->read ordered via lgkmcnt

  // ---- layer 2 (+3 folded): h2 = sin(30*(h1@W2+b2)); pred = h2@W3 ----
  float pacc[2][4];
  #pragma unroll
  for(int rt=0;rt<2;rt++)
    #pragma unroll
    for(int rr=0;rr<4;rr++) pacc[rt][rr]=0.f;

  #pragma unroll 1
  for(int cg=0; cg<4; cg++){
    f32x4 acc[2][4];
    const f32x4 zv = {0.f,0.f,0.f,0.f};
    #pragma unroll
    for(int rt=0;rt<2;rt++)
      #pragma unroll
      for(int nt=0;nt<4;nt++) acc[rt][nt] = zv;

    #pragma unroll
    for(int ks=0; ks<8; ks++){
      s16x8 a2[2];
      #pragma unroll
      for(int rt=0;rt<2;rt++){
        const int m  = rt*16 + ln;
        const int gk = ks*4 + q;
        a2[rt] = *(const s16x8*)(hlds + m*256 + ((gk ^ (m&7))<<3));
      }
      s16x8 b2f[4];
      #pragma unroll
      for(int nt=0;nt<4;nt++){
        const int n = cg*64 + nt*16 + ln;
        b2f[nt] = *(const s16x8*)(W2T + n*256 + ks*32 + q*8);
      }
      #pragma unroll
      for(int rt=0;rt<2;rt++)
        #pragma unroll
        for(int nt=0;nt<4;nt++)
          acc[rt][nt] = __builtin_amdgcn_mfma_f32_16x16x32_bf16(a2[rt], b2f[nt], acc[rt][nt], 0,0,0);
    }
    #pragma unroll
    for(int nt=0;nt<4;nt++){
      const int n = cg*64 + nt*16 + ln;
      const float b2v = b2[n];
      const float w3v = W3[n];
      #pragma unroll
      for(int rt=0;rt<2;rt++)
        #pragma unroll
        for(int rr=0;rr<4;rr++){
          const float h2 = __sinf(30.0f*(acc[rt][nt][rr] + b2v));
          pacc[rt][rr] += h2*w3v;
        }
    }
  }

  // reduce over the 16 n-lanes (xor within ln bits keeps q fixed)
  #pragma unroll
  for(int rt=0;rt<2;rt++)
    #pragma unroll
    for(int rr=0;rr<4;rr++){
      float v = pacc[rt][rr];
      v += __shfl_xor(v, 1, 64);
      v += __shfl_xor(v, 2, 64);
      v += __shfl_xor(v, 4, 64);
      v += __shfl_xor(v, 8, 64);
      pacc[rt][rr] = v;
    }

  // ---- fused lerp: rows (2s, 2s+1) = (floor, ceil) of one pixel ----
  if(ln==0){
    #pragma unroll
    for(int rt=0;rt<2;rt++){
      #pragma unroll
      for(int s=0;s<2;s++){
        const int m0 = rt*16 + q*4 + 2*s;
        const float tcp = T.tcm[rt][2*s];
        const int tip = (int)floorf((tcp+1.0f)/dstep);
        const float fci = (float)((double)tip*(2.0/31.0) - 1.0);
        const float tau = (tcp - fci)/dstep;
        const unsigned px = (tile*32u + (unsigned)m0)>>1;
        out[px] = pacc[rt][2*s]*(1.0f-tau) + pacc[rt][2*s+1]*tau + b3v;
      }
    }
  }
}

__global__ __launch_bounds__(64) void mlp_kernel(
  const float* __restrict__ tcoord,
  const short* __restrict__ fhi, const short* __restrict__ flo,
  const short* __restrict__ W1T, const short* __restrict__ W1L,
  const float* __restrict__ W1,  const float* __restrict__ b1,
  const short* __restrict__ W2T, const float* __restrict__ b2,
  const float* __restrict__ W3,  const float* __restrict__ b3,
  float* __restrict__ out)
{
  __shared__ __align__(16) short hlds[32*256];  // 16 KB, private to this wave
  const int lane = threadIdx.x;  // 0..63
  const int q  = lane>>4;
  const int ln = lane&15;
  const unsigned tile0 = blockIdx.x*4u;
  const float b3v = b3[0];

  TileA cur, nxt;
  load_tile(tile0+0, lane, q, ln, tcoord, fhi, flo, cur);
  #pragma unroll
  for(int t=0; t<4; t++){
    if(t<3) load_tile(tile0+t+1, lane, q, ln, tcoord, fhi, flo, nxt);
    compute_tile(cur, tile0+t, lane, q, ln,
                 W1T, W1L, W1, b1, W2T, b2, W3, b3v, hlds, out);
    if(t<3) cur = nxt;
  }
}

extern "C" void kernel_launch(void* const* d_in, const int* in_sizes, int n_in,
                              void* d_out, int out_size, void* d_ws, size_t ws_size,
                              hipStream_t stream){
  const float* xr     = (const float*)d_in[0];
  const float* xi     = (const float*)d_in[1];
  const float* tcoord = (const float*)d_in[2];
  const float* enc_w  = (const float*)d_in[3];
  const float* enc_b  = (const float*)d_in[4];
  const float* W1     = (const float*)d_in[5];
  const float* b1     = (const float*)d_in[6];
  const float* W2     = (const float*)d_in[7];
  const float* b2     = (const float*)d_in[8];
  const float* W3     = (const float*)d_in[9];
  const float* b3     = (const float*)d_in[10];

  char* ws = (char*)d_ws;
  short* fhi  = (short*)(ws);
  short* flo  = (short*)(ws + 75497472);
  short* W1T  = (short*)(ws + 150994944);
  short* W1L  = (short*)(ws + 151027712);
  short* W2T  = (short*)(ws + 151060480);
  float* out  = (float*)d_out;

  hipLaunchKernelGGL(prep1_kernel, dim3(64),   dim3(256), 0, stream, W1, W1T, W1L);
  hipLaunchKernelGGL(prep2_kernel, dim3(256),  dim3(256), 0, stream, W2, W2T);
  hipLaunchKernelGGL(conv_kernel,  dim3(2304), dim3(256), 0, stream, xr, xi, enc_w, enc_b, fhi, flo);
  hipLaunchKernelGGL(mlp_kernel,   dim3(9216), dim3(64),  0, stream, tcoord, fhi, flo,
                     W1T, W1L, W1, b1, W2T, b2, W3, b3, out);
}